// Round 9
// baseline (72.944 us; speedup 1.0000x reference)
//
#include <hip/hip_runtime.h>

#define EPS 1e-7f
#define LOG2E 1.44269504088896340736f

typedef float f32x2 __attribute__((ext_vector_type(2)));
typedef float f32x4 __attribute__((ext_vector_type(4)));

constexpr int BLOCK = 512;         // 8 waves/block, 2 blocks/CU
constexpr int JJ    = 4;           // lane-fast j slots
constexpr int JR    = 4;           // j's per thread -> 4 evals per LDS read
constexpr int JB    = JJ * JR;     // 16 outputs per block
constexpr int SS    = BLOCK / JJ;  // 128 i-segments per block
constexpr int CHUNK = 1024;        // points per LDS chunk
constexpr int PTS   = CHUNK / SS;  // 8 points per segment
constexpr int ROW   = 12;          // 12-float rows: 16B-aligned b128, uniform 2-way banks (free)
constexpr int REPS  = 1;           // R4 ran this exact kernel at REPS=4: 58.66us -> 14.66us/pass.
                                   // REPS=1 is the production setting; this run discriminates the
                                   // additive-overhead model (predict ~62us total) vs harness-floor
                                   // (~73us) -- see session journal R8 post-mortem.

// R4 structure, unchanged (best direct per-pass measurement of the session).
// Thread = (jj, ss). SoA LDS (x,y,s,o); ds_read_b128 per 4 points, uniform
// 2-way bank aliasing = free (m136). Each b128 feeds 4 pts x 4 j = 16 evals.
// Packed f32x2 math: per 2 evals 3 pk_fma + 2 exp + 1 pk_fma + 1 pk_add.
// Register prefetch of next chunk flies under compute; 2 barriers/chunk.
__global__ __launch_bounds__(BLOCK, 4) void nw_block(
    const float2* __restrict__ x,        // M x 2 query points
    const float2* __restrict__ inputs,   // N x 2 data points
    const float*  __restrict__ outputs,  // N
    const float*  __restrict__ bw,       // M
    float*        __restrict__ out,      // M
    int N, int M)
{
    __shared__ __align__(16) float sX[SS][ROW];
    __shared__ __align__(16) float sY[SS][ROW];
    __shared__ __align__(16) float sS[SS][ROW];
    __shared__ __align__(16) float sO[SS][ROW];
    __shared__ float2 red[SS][JB];       // 16 KB

    const int tid = threadIdx.x;
    const int jj  = tid & (JJ - 1);
    const int ss  = tid >> 2;            // tid / JJ

    // per-thread coefficient pairs (splat): t = c0*s + c1*px + c2*py + c3, k<0 folded
    f32x2 c0p[JR], c1p[JR], c2p[JR], c3p[JR];
    #pragma unroll
    for (int r = 0; r < JR; ++r) {
        const int j = blockIdx.x * JB + jj + r * JJ;
        float k = 0.f, v1 = 0.f, v2 = 0.f, v3 = 0.f;
        if (j < M) {
            float2 xj = x[j];
            float  b  = bw[j];
            k  = -LOG2E / (2.0f * b * b);              // < 0
            v1 = -2.0f * k * xj.x;
            v2 = -2.0f * k * xj.y;
            v3 = k * fmaf(xj.x, xj.x, xj.y * xj.y);
        }
        c0p[r] = {k, k}; c1p[r] = {v1, v1}; c2p[r] = {v2, v2}; c3p[r] = {v3, v3};
    }

    f32x2 nump[JR], denp[JR];
    #pragma unroll
    for (int r = 0; r < JR; ++r) { nump[r] = {0.f, 0.f}; denp[r] = {0.f, 0.f}; }

    // register prefetch of chunk 0: thread t owns points (2t, 2t+1)
    const float4* in4  = (const float4*)inputs;   // 2 points per float4
    const float2* out2 = (const float2*)outputs;
    float4 pin  = make_float4(0.f, 0.f, 0.f, 0.f);
    float2 pout = make_float2(0.f, 0.f);
    if (2 * tid + 1 < N) { pin = in4[tid]; pout = out2[tid]; }

    for (int rep = 0; rep < REPS; ++rep) {
        for (int base = 0; base < N; base += CHUNK) {
            const int cnt = min(CHUNK, N - base);
            // stage pair (2t, 2t+1) -> row (2t)>>3, slots ((2t)&7, +1), b64 SoA writes
            {
                const int  r0 = tid >> 2;
                const int  s0 = (2 * tid) & (PTS - 1);
                const bool v0 = (2 * tid) < cnt;
                const bool v1 = (2 * tid + 1) < cnt;
                f32x2 xp = {v0 ? pin.x : 0.f, v1 ? pin.z : 0.f};
                f32x2 yp = {v0 ? pin.y : 0.f, v1 ? pin.w : 0.f};
                f32x2 sp = {v0 ? fmaf(pin.x, pin.x, pin.y * pin.y) : 3.0e38f,  // c0*s -> -inf -> w=0
                            v1 ? fmaf(pin.z, pin.z, pin.w * pin.w) : 3.0e38f};
                f32x2 op = {v0 ? pout.x : 0.f, v1 ? pout.y : 0.f};
                *(f32x2*)&sX[r0][s0] = xp;
                *(f32x2*)&sY[r0][s0] = yp;
                *(f32x2*)&sS[r0][s0] = sp;
                *(f32x2*)&sO[r0][s0] = op;
            }
            __syncthreads();

            // prefetch next chunk (wraps to chunk 0 across reps); flies under compute
            {
                int nb = base + CHUNK;
                if (nb >= N) nb = 0;
                const int i0 = (nb >> 1) + tid;
                if (2 * i0 + 1 < N) { pin = in4[i0]; pout = out2[i0]; }
            }

            // compute: PTS points as PTS/4 b128 groups x JR j's
            #pragma unroll
            for (int g = 0; g < PTS / 4; ++g) {
                f32x4 xq = *(const f32x4*)&sX[ss][4 * g];   // ds_read_b128, 2-way = free
                f32x4 yq = *(const f32x4*)&sY[ss][4 * g];
                f32x4 sq = *(const f32x4*)&sS[ss][4 * g];
                f32x4 oq = *(const f32x4*)&sO[ss][4 * g];
                f32x2 x0 = {xq.x, xq.y}, x1 = {xq.z, xq.w};
                f32x2 y0 = {yq.x, yq.y}, y1 = {yq.z, yq.w};
                f32x2 s0 = {sq.x, sq.y}, s1 = {sq.z, sq.w};
                f32x2 o0 = {oq.x, oq.y}, o1 = {oq.z, oq.w};
                #pragma unroll
                for (int r = 0; r < JR; ++r) {
                    f32x2 ta = __builtin_elementwise_fma(c2p[r], y0, c3p[r]);
                    ta = __builtin_elementwise_fma(c1p[r], x0, ta);
                    ta = __builtin_elementwise_fma(c0p[r], s0, ta);
                    f32x2 tb = __builtin_elementwise_fma(c2p[r], y1, c3p[r]);
                    tb = __builtin_elementwise_fma(c1p[r], x1, tb);
                    tb = __builtin_elementwise_fma(c0p[r], s1, tb);
                    f32x2 wa, wb;
                    wa.x = __builtin_amdgcn_exp2f(ta.x);
                    wa.y = __builtin_amdgcn_exp2f(ta.y);
                    wb.x = __builtin_amdgcn_exp2f(tb.x);
                    wb.y = __builtin_amdgcn_exp2f(tb.y);
                    nump[r] = __builtin_elementwise_fma(wa, o0, nump[r]);
                    nump[r] = __builtin_elementwise_fma(wb, o1, nump[r]);
                    denp[r] += wa + wb;
                }
            }
            __syncthreads();
        }
    }

    // two-stage block reduction across the 128 segments
    #pragma unroll
    for (int r = 0; r < JR; ++r)
        red[ss][jj + r * JJ] = make_float2(nump[r].x + nump[r].y,
                                           denp[r].x + denp[r].y);
    __syncthreads();
    if (tid < 16 * JB) {                 // 256 threads: (s2, slot)
        const int s2   = tid >> 4;       // 0..15
        const int slot = tid & 15;
        float n = 0.f, d = 0.f;
        #pragma unroll
        for (int k = 0; k < SS / 16; ++k) {
            n += red[s2 + 16 * k][slot].x;
            d += red[s2 + 16 * k][slot].y;
        }
        red[s2][slot] = make_float2(n, d);
    }
    __syncthreads();
    if (tid < JB) {
        float n = 0.f, d = 0.f;
        #pragma unroll
        for (int s = 0; s < 16; ++s) {
            n += red[s][tid].x;
            d += red[s][tid].y;
        }
        const int jo = blockIdx.x * JB + tid;
        if (jo < M) out[jo] = n / (d + EPS);
    }
}

extern "C" void kernel_launch(void* const* d_in, const int* in_sizes, int n_in,
                              void* d_out, int out_size, void* d_ws, size_t ws_size,
                              hipStream_t stream) {
    // setup_inputs() dict order: x (M*2), inputs (N*2), outputs (N), bandwidth (M)
    const float2* x       = (const float2*)d_in[0];
    const float2* inputs  = (const float2*)d_in[1];
    const float*  outputs = (const float*) d_in[2];
    const float*  bwv     = (const float*) d_in[3];
    const int N = in_sizes[2];   // outputs element count
    const int M = in_sizes[3];   // bandwidth element count
    float*        out     = (float*)d_out;

    dim3 grid((M + JB - 1) / JB);    // 512 blocks @ M=8192 -> 2 blocks/CU
    nw_block<<<grid, BLOCK, 0, stream>>>(x, inputs, outputs, bwv, out, N, M);
}